// Round 1
// baseline (104.473 us; speedup 1.0000x reference)
//
#include <hip/hip_runtime.h>
#include <math.h>

// QuantumPolicy: MLP(6->64->6) -> 6-qubit RY/CNOT circuit (4 layers) -> Z exp
// -> softmax policy head (4) + value head (1).
// One thread per batch element; the 2^6=64-amplitude statevector lives
// entirely in registers (all loops fully unrolled, indices compile-time).
// CNOTs are register renames (free); RYs are FMA chains. VALU-bound.

#define NQ 6
#define NL 4
#define NA 4
#define PD 64
#define NS 64   // 2^NQ

__global__ __launch_bounds__(256) void qpolicy_kernel(
    const float* __restrict__ x,
    const float* __restrict__ W1,
    const float* __restrict__ b1,
    const float* __restrict__ W2,
    const float* __restrict__ b2,
    const float* __restrict__ qw,
    const float* __restrict__ Wp,
    const float* __restrict__ bp,
    const float* __restrict__ Wv,
    const float* __restrict__ bv,
    float* __restrict__ out,
    int B)
{
    const int tid = blockIdx.x * blockDim.x + threadIdx.x;

    // ---- load x[tid, 0:6]  (stride 24 B, 8-byte aligned -> 3x float2)
    float xi[NQ];
    {
        const float2* xv = reinterpret_cast<const float2*>(x + (size_t)tid * NQ);
        float2 a = xv[0], b = xv[1], c = xv[2];
        xi[0] = a.x; xi[1] = a.y; xi[2] = b.x; xi[3] = b.y; xi[4] = c.x; xi[5] = c.y;
    }

    // ---- MLP layer 1: h = relu(x @ W1^T + b1)   (weights: uniform s_loads)
    float h[PD];
#pragma unroll
    for (int j = 0; j < PD; ++j) {
        float acc = b1[j];
#pragma unroll
        for (int q = 0; q < NQ; ++q) acc = fmaf(xi[q], W1[j * NQ + q], acc);
        h[j] = fmaxf(acc, 0.0f);
    }

    // ---- MLP layer 2: xp = relu(h @ W2^T + b2)
    float xp[NQ];
#pragma unroll
    for (int i = 0; i < NQ; ++i) {
        float acc = b2[i];
#pragma unroll
        for (int j = 0; j < PD; ++j) acc = fmaf(h[j], W2[i * PD + j], acc);
        xp[i] = fmaxf(acc, 0.0f);
    }

    // ---- AngleEmbedding: RY(xp[q]) on |0..0> gives a product state.
    // st[idx] = prod_q (bit_q(idx) ? sin(xp[q]/2) : cos(xp[q]/2)),
    // with qubit q at bit position (5-q) (MSB-first, row-major (2,)*6 flatten).
    float cq[NQ], sq[NQ];
#pragma unroll
    for (int q = 0; q < NQ; ++q) {
        __sincosf(0.5f * xp[q], &sq[q], &cq[q]);
    }
    float st[NS];
    st[0] = 1.0f;
#pragma unroll
    for (int q = 0; q < NQ; ++q) {
        const int sz = 1 << q;   // valid entries before this step
#pragma unroll
        for (int k = sz - 1; k >= 0; --k) {  // downward: writes never clobber unread
            float v = st[k];
            st[2 * k]     = v * cq[q];
            st[2 * k + 1] = v * sq[q];
        }
    }

    // ---- 4 layers of [CNOT ring] + [RY(qw[l,i]) on each qubit]
#pragma unroll
    for (int l = 0; l < NL; ++l) {
        // CNOT(i, (i+1)%6), applied sequentially. Pure amplitude swaps:
        // compile-time indices -> register renaming, zero VALU cost.
#pragma unroll
        for (int i = 0; i < NQ; ++i) {
            const int c = i, t = (i + 1) % NQ;
            const int cm = 1 << (5 - c), tm = 1 << (5 - t);
#pragma unroll
            for (int idx = 0; idx < NS; ++idx) {
                if ((idx & cm) && !(idx & tm)) {
                    float tmp = st[idx];
                    st[idx] = st[idx | tm];
                    st[idx | tm] = tmp;
                }
            }
        }
        // RY rotations with scalar (wave-uniform) angles; recompute trig per
        // layer to keep register lifetime short.
        float cw[NQ], sw[NQ];
#pragma unroll
        for (int i = 0; i < NQ; ++i) {
            __sincosf(0.5f * qw[l * NQ + i], &sw[i], &cw[i]);
        }
#pragma unroll
        for (int i = 0; i < NQ; ++i) {
            const int qm = 1 << (5 - i);
            const float c = cw[i], s = sw[i];
#pragma unroll
            for (int idx = 0; idx < NS; ++idx) {
                if (!(idx & qm)) {
                    float a0 = st[idx], a1 = st[idx | qm];
                    st[idx]      = fmaf(c, a0, -(s * a1));
                    st[idx | qm] = fmaf(c, a1,  (s * a0));
                }
            }
        }
    }

    // ---- probabilities (in place) and Z expectations
#pragma unroll
    for (int idx = 0; idx < NS; ++idx) st[idx] = st[idx] * st[idx];
    float z[NQ];
#pragma unroll
    for (int q = 0; q < NQ; ++q) {
        const int qm = 1 << (5 - q);
        float acc = 0.0f;
#pragma unroll
        for (int idx = 0; idx < NS; ++idx) {
            acc += (idx & qm) ? -st[idx] : st[idx];  // folds to add/sub
        }
        z[q] = acc;
    }

    // ---- policy head: softmax(z @ Wp^T + bp)
    float logits[NA];
#pragma unroll
    for (int a = 0; a < NA; ++a) {
        float acc = bp[a];
#pragma unroll
        for (int q = 0; q < NQ; ++q) acc = fmaf(z[q], Wp[a * NQ + q], acc);
        logits[a] = acc;
    }
    float m = logits[0];
#pragma unroll
    for (int a = 1; a < NA; ++a) m = fmaxf(m, logits[a]);
    float e[NA];
    float esum = 0.0f;
#pragma unroll
    for (int a = 0; a < NA; ++a) { e[a] = __expf(logits[a] - m); esum += e[a]; }
    const float inv = 1.0f / esum;

    float4 pol;
    pol.x = e[0] * inv; pol.y = e[1] * inv; pol.z = e[2] * inv; pol.w = e[3] * inv;
    reinterpret_cast<float4*>(out)[tid] = pol;          // policy: (B,4) row-major

    // ---- value head
    float v = bv[0];
#pragma unroll
    for (int q = 0; q < NQ; ++q) v = fmaf(z[q], Wv[q], v);
    out[(size_t)B * NA + tid] = v;                      // value: (B,) after policy
}

extern "C" void kernel_launch(void* const* d_in, const int* in_sizes, int n_in,
                              void* d_out, int out_size, void* d_ws, size_t ws_size,
                              hipStream_t stream) {
    const float* x  = (const float*)d_in[0];
    const float* W1 = (const float*)d_in[1];
    const float* b1 = (const float*)d_in[2];
    const float* W2 = (const float*)d_in[3];
    const float* b2 = (const float*)d_in[4];
    const float* qw = (const float*)d_in[5];
    const float* Wp = (const float*)d_in[6];
    const float* bp = (const float*)d_in[7];
    const float* Wv = (const float*)d_in[8];
    const float* bv = (const float*)d_in[9];
    float* out = (float*)d_out;

    const int B = in_sizes[0] / NQ;      // 262144
    dim3 block(256);
    dim3 grid((B + 255) / 256);
    hipLaunchKernelGGL(qpolicy_kernel, grid, block, 0, stream,
                       x, W1, b1, W2, b2, qw, Wp, bp, Wv, bv, out, B);
}

// Round 2
// 98.900 us; speedup vs baseline: 1.0564x; 1.0564x over previous
//
#include <hip/hip_runtime.h>
#include <math.h>

// QuantumPolicy: MLP(6->64->6) -> 6-qubit RY/CNOT circuit (4 layers) -> Z exp
// -> softmax policy head (4) + value head (1).
//
// One thread per batch element. Statevector stored as 32 x float2 (packed
// along qubit5 = flat LSB) so 5 of 6 per-qubit RY rotations become pure
// lane-parallel v_pk_fma_f32. Rotations use the exact 3-shear decomposition
// (3 FMAs/pair instead of mul+fma x2), with angle range-reduction h>pi/2 ->
// h-pi (the induced global -1 on the state is killed by the final squaring),
// keeping |t|=|tan(h/2)| <= 1 for fp32 stability.
// CNOTs are compile-time register renames (free). Z-expectations via a shared
// partial-sum tree: z_j = 2*S_j - T. VALU-issue-bound; no LDS, no MFMA.

#define NQ 6
#define NL 4
#define NA 4
#define PD 64

typedef float v2 __attribute__((ext_vector_type(2)));

__device__ __forceinline__ v2 mk2(float a, float b) { v2 r; r.x = a; r.y = b; return r; }
__device__ __forceinline__ v2 pkfma(v2 a, v2 b, v2 c) { return __builtin_elementwise_fma(a, b, c); }

__global__ __launch_bounds__(256) void qpolicy_kernel(
    const float* __restrict__ x,
    const float* __restrict__ W1,
    const float* __restrict__ b1,
    const float* __restrict__ W2,
    const float* __restrict__ b2,
    const float* __restrict__ qw,
    const float* __restrict__ Wp,
    const float* __restrict__ bp,
    const float* __restrict__ Wv,
    const float* __restrict__ bv,
    float* __restrict__ out,
    int B)
{
    const int tid = blockIdx.x * blockDim.x + threadIdx.x;

    // ---- load x[tid, 0:6] as 3 x float2 (24 B stride, 8-aligned)
    const v2* xv = reinterpret_cast<const v2*>(x + (size_t)tid * NQ);
    const v2 x01 = xv[0], x23 = xv[1], x45 = xv[2];

    const v2* W1v = reinterpret_cast<const v2*>(W1);  // rows of 6 = 3 v2, 8-aligned
    const v2* W2v = reinterpret_cast<const v2*>(W2);  // rows of 64 = 32 v2

    // ---- MLP1: h = relu(x @ W1^T + b1), packed over the input dim.
    // Weight pairs are contiguous -> uniform s_load_dwordx2 SGPR-pair operands.
    v2 h2[PD / 2];
#pragma unroll
    for (int j2 = 0; j2 < PD / 2; ++j2) {
        float hj[2];
#pragma unroll
        for (int u = 0; u < 2; ++u) {
            const int j = 2 * j2 + u;
            v2 acc = mk2(b1[j], 0.0f);
            acc = pkfma(x01, W1v[j * 3 + 0], acc);
            acc = pkfma(x23, W1v[j * 3 + 1], acc);
            acc = pkfma(x45, W1v[j * 3 + 2], acc);
            hj[u] = fmaxf(acc.x + acc.y, 0.0f);
        }
        h2[j2] = mk2(hj[0], hj[1]);
    }

    // ---- MLP2: xp = relu(h @ W2^T + b2), packed over the hidden dim.
    float xp[NQ];
#pragma unroll
    for (int i = 0; i < NQ; ++i) {
        v2 acc = mk2(b2[i], 0.0f);
#pragma unroll
        for (int k = 0; k < PD / 2; ++k) acc = pkfma(h2[k], W2v[i * (PD / 2) + k], acc);
        xp[i] = fmaxf(acc.x + acc.y, 0.0f);
    }

    // ---- AngleEmbedding: product state. Qubit q sits at flat bit (5-q);
    // k-space (flat>>1) holds qubits 0..4 (qubit q at k-bit 4-q), qubit5 in lanes.
    float cq[NQ], sq[NQ];
#pragma unroll
    for (int q = 0; q < NQ; ++q) __sincosf(0.5f * xp[q], &sq[q], &cq[q]);

    float pr[32];
    pr[0] = 1.0f;
#pragma unroll
    for (int q = 0; q < 5; ++q) {
        const int sz = 1 << q;
#pragma unroll
        for (int k = sz - 1; k >= 0; --k) {
            const float v = pr[k];
            pr[2 * k]     = v * cq[q];
            pr[2 * k + 1] = v * sq[q];
        }
    }
    v2 st[32];
    const v2 cs5 = mk2(cq[5], sq[5]);
#pragma unroll
    for (int k = 0; k < 32; ++k) st[k] = mk2(pr[k], pr[k]) * cs5;

    // ---- 4 layers of [CNOT ring] + [RY(qw[l,i])]
#pragma unroll
    for (int l = 0; l < NL; ++l) {
        // CNOT(i,i+1), i=0..3: both qubits in k-space -> whole-register renames.
#pragma unroll
        for (int i = 0; i < 4; ++i) {
            const int mc = 1 << (4 - i), mt = 1 << (3 - i);
#pragma unroll
            for (int k = 0; k < 32; ++k) {
                if ((k & mc) && !(k & mt)) {
                    v2 tmp = st[k]; st[k] = st[k | mt]; st[k | mt] = tmp;
                }
            }
        }
        // CNOT(4,5): control at k-bit0, target = lane swap.
#pragma unroll
        for (int k = 0; k < 32; ++k) {
            if (k & 1) st[k] = __builtin_shufflevector(st[k], st[k], 1, 0);
        }
        // CNOT(5,0): control = lane1, target = k-bit4 -> swap hi lanes across regs.
#pragma unroll
        for (int k = 0; k < 16; ++k) {
            const float tmp = st[k].y; st[k].y = st[k | 16].y; st[k | 16].y = tmp;
        }

        // Per-layer rotation constants: t = tan(h/2), s = sin(h), h range-reduced
        // into (-pi/2, pi/2] (global sign flip is irrelevant after squaring).
        float tv[NQ], sv[NQ];
#pragma unroll
        for (int i = 0; i < NQ; ++i) {
            float hh = 0.5f * qw[l * NQ + i];
            hh = (hh > 1.5707963f) ? (hh - 3.14159265358979f) : hh;
            float sh, ch;
            __sincosf(hh, &sh, &ch);
            sv[i] = sh;
            tv[i] = sh * __builtin_amdgcn_rcpf(1.0f + ch);  // stable: 1+ch in [1,2]
        }

        // RY on qubits 0..4: 3 packed shears per register pair.
#pragma unroll
        for (int i = 0; i < 5; ++i) {
            const int m = 1 << (4 - i);
            const v2 vnt = mk2(-tv[i], -tv[i]);
            const v2 vs  = mk2(sv[i], sv[i]);
#pragma unroll
            for (int k = 0; k < 32; ++k) {
                if (!(k & m)) {
                    v2 a = st[k], b = st[k | m];
                    a = pkfma(vnt, b, a);
                    b = pkfma(vs, a, b);
                    a = pkfma(vnt, b, a);
                    st[k] = a; st[k | m] = b;
                }
            }
        }
        // RY on qubit 5: intra-register (scalar shears).
        {
            const float nt = -tv[5], s5 = sv[5];
#pragma unroll
            for (int k = 0; k < 32; ++k) {
                float a0 = st[k].x, a1 = st[k].y;
                a0 = fmaf(nt, a1, a0);
                a1 = fmaf(s5, a0, a1);
                a0 = fmaf(nt, a1, a0);
                st[k] = mk2(a0, a1);
            }
        }
    }

    // ---- probabilities + Z expectations via shared partial-sum tree.
    // z_j = 2*S_j - T, S_j = prob(qubit j = 0), T = total prob.
    float a[32];
    float S5 = 0.0f;
#pragma unroll
    for (int k = 0; k < 32; ++k) {
        const v2 p = st[k] * st[k];
        a[k] = p.x + p.y;
        S5 += p.x;
    }
    float S0 = 0.0f;
#pragma unroll
    for (int k = 0; k < 16; ++k) S0 += a[k];
    float b16[16];
#pragma unroll
    for (int k = 0; k < 16; ++k) b16[k] = a[k] + a[k | 16];
    float S1 = 0.0f;
#pragma unroll
    for (int k = 0; k < 8; ++k) S1 += b16[k];
    float b8[8];
#pragma unroll
    for (int k = 0; k < 8; ++k) b8[k] = b16[k] + b16[k | 8];
    const float S2 = b8[0] + b8[1] + b8[2] + b8[3];
    float b4[4];
#pragma unroll
    for (int k = 0; k < 4; ++k) b4[k] = b8[k] + b8[k | 4];
    const float S3 = b4[0] + b4[1];
    float b2a[2];
    b2a[0] = b4[0] + b4[2];
    b2a[1] = b4[1] + b4[3];
    const float S4 = b2a[0];
    const float T = b2a[0] + b2a[1];

    float z[NQ];
    z[0] = fmaf(2.0f, S0, -T);
    z[1] = fmaf(2.0f, S1, -T);
    z[2] = fmaf(2.0f, S2, -T);
    z[3] = fmaf(2.0f, S3, -T);
    z[4] = fmaf(2.0f, S4, -T);
    z[5] = fmaf(2.0f, S5, -T);

    // ---- policy head: softmax(z @ Wp^T + bp)
    float logits[NA];
#pragma unroll
    for (int aidx = 0; aidx < NA; ++aidx) {
        float acc = bp[aidx];
#pragma unroll
        for (int q = 0; q < NQ; ++q) acc = fmaf(z[q], Wp[aidx * NQ + q], acc);
        logits[aidx] = acc;
    }
    float m = logits[0];
#pragma unroll
    for (int aidx = 1; aidx < NA; ++aidx) m = fmaxf(m, logits[aidx]);
    float e[NA];
    float esum = 0.0f;
#pragma unroll
    for (int aidx = 0; aidx < NA; ++aidx) { e[aidx] = __expf(logits[aidx] - m); esum += e[aidx]; }
    const float inv = 1.0f / esum;

    float4 pol;
    pol.x = e[0] * inv; pol.y = e[1] * inv; pol.z = e[2] * inv; pol.w = e[3] * inv;
    reinterpret_cast<float4*>(out)[tid] = pol;          // policy: (B,4)

    float v = bv[0];
#pragma unroll
    for (int q = 0; q < NQ; ++q) v = fmaf(z[q], Wv[q], v);
    out[(size_t)B * NA + tid] = v;                      // value: (B,)
}

extern "C" void kernel_launch(void* const* d_in, const int* in_sizes, int n_in,
                              void* d_out, int out_size, void* d_ws, size_t ws_size,
                              hipStream_t stream) {
    const float* x  = (const float*)d_in[0];
    const float* W1 = (const float*)d_in[1];
    const float* b1 = (const float*)d_in[2];
    const float* W2 = (const float*)d_in[3];
    const float* b2 = (const float*)d_in[4];
    const float* qw = (const float*)d_in[5];
    const float* Wp = (const float*)d_in[6];
    const float* bp = (const float*)d_in[7];
    const float* Wv = (const float*)d_in[8];
    const float* bv = (const float*)d_in[9];
    float* out = (float*)d_out;

    const int B = in_sizes[0] / NQ;      // 262144
    dim3 block(256);
    dim3 grid((B + 255) / 256);
    hipLaunchKernelGGL(qpolicy_kernel, grid, block, 0, stream,
                       x, W1, b1, W2, b2, qw, Wp, bp, Wv, bv, out, B);
}